// Round 1
// baseline (665.010 us; speedup 1.0000x reference)
//
#include <hip/hip_runtime.h>
#include <hip/hip_bf16.h>
#include <stdint.h>

// Problem constants
#define BQ 128    // batch
#define NJ 512    // input capsules j
#define DD 300    // input dim
#define NC 10     // num_capsule i
#define DC 64     // dim_capsule k
#define MM 640    // NC*DC
#define KP 320    // K padded to multiple of 32
#define RT 5      // routing iterations

typedef __attribute__((ext_vector_type(8))) short short8;   // 8 bf16 = 4 VGPRs
typedef __attribute__((ext_vector_type(4))) float f32x4;

// ---------------- cast / init kernels ----------------

__global__ void k_cast_x(const float* __restrict__ x, __hip_bfloat16* __restrict__ xb) {
    int idx = blockIdx.x * 256 + threadIdx.x;          // 65536*320 total, exact grid
    int row = idx / KP, col = idx - row * KP;
    float v = (col < DD) ? x[(size_t)row * DD + col] : 0.f;
    xb[idx] = __float2bfloat16(v);
}

__global__ void k_cast_w(const float* __restrict__ w, __hip_bfloat16* __restrict__ wt) {
    int idx = blockIdx.x * 256 + threadIdx.x;          // 640*320 total, exact grid
    int m = idx / KP, k = idx - m * KP;
    float v = (k < DD) ? w[(size_t)k * MM + m] : 0.f;  // transpose: Wt[m][k] = W[k][m]
    wt[idx] = __float2bfloat16(v);
}

__global__ void k_zero(float4* __restrict__ p) {       // zero b_logits (re-poisoned each call)
    p[blockIdx.x * 256 + threadIdx.x] = make_float4(0.f, 0.f, 0.f, 0.f);
}

// ---------------- MFMA GEMM: u[65536][640] = xb[65536][320] * Wt^T ----------------
// 128x128 tile, BK=32, 256 threads (4 waves, 2x2 of 64x64), global_load_lds width 16.

__global__ __launch_bounds__(256)
void k_gemm(const __hip_bfloat16* __restrict__ A,   // [65536][KP] row-major
            const __hip_bfloat16* __restrict__ Bt,  // [640][KP] row-major (W transposed)
            __hip_bfloat16* __restrict__ C) {       // [65536][640] row-major, bf16
    __shared__ __align__(16) __hip_bfloat16 As[128 * 32];
    __shared__ __align__(16) __hip_bfloat16 Bs[128 * 32];

    const int m0 = blockIdx.y * 128;
    const int n0 = blockIdx.x * 128;
    const int t  = threadIdx.x;
    const int w  = t >> 6, lane = t & 63;
    const int wrow = (w >> 1) * 64, wcol = (w & 1) * 64;
    const int quad = lane >> 4, r = lane & 15;

    f32x4 acc[4][4] = {};

    // staging source pointers: thread t loads 8 bf16 (16 B); rows t/4, cols (t%4)*8
    const __hip_bfloat16* ag = A  + (size_t)(m0 + (t >> 2)) * KP + (t & 3) * 8;
    const __hip_bfloat16* bg = Bt + (size_t)(n0 + (t >> 2)) * KP + (t & 3) * 8;

    for (int kt = 0; kt < KP / 32; ++kt) {
        __syncthreads();   // previous tile's LDS reads complete
        // LDS layout row-major [128][32]; dest offset = issue*4096B + t*16B (lane-contiguous)
        __builtin_amdgcn_global_load_lds(
            (const __attribute__((address_space(1))) void*)(ag + kt * 32),
            (__attribute__((address_space(3))) void*)(&As[t * 8]), 16, 0, 0);
        __builtin_amdgcn_global_load_lds(
            (const __attribute__((address_space(1))) void*)(ag + 64 * KP + kt * 32),
            (__attribute__((address_space(3))) void*)(&As[2048 + t * 8]), 16, 0, 0);
        __builtin_amdgcn_global_load_lds(
            (const __attribute__((address_space(1))) void*)(bg + kt * 32),
            (__attribute__((address_space(3))) void*)(&Bs[t * 8]), 16, 0, 0);
        __builtin_amdgcn_global_load_lds(
            (const __attribute__((address_space(1))) void*)(bg + 64 * KP + kt * 32),
            (__attribute__((address_space(3))) void*)(&Bs[2048 + t * 8]), 16, 0, 0);
        __syncthreads();   // compiler emits vmcnt(0) before s_barrier -> staging done

        // A frag: lane holds A[m = r][k = quad*8 + j]; B frag: B[k = quad*8 + j][n = r]
        short8 af[4], bf[4];
#pragma unroll
        for (int mi = 0; mi < 4; ++mi)
            af[mi] = *(const short8*)&As[(wrow + mi * 16 + r) * 32 + quad * 8];
#pragma unroll
        for (int ni = 0; ni < 4; ++ni)
            bf[ni] = *(const short8*)&Bs[(wcol + ni * 16 + r) * 32 + quad * 8];
#pragma unroll
        for (int mi = 0; mi < 4; ++mi)
#pragma unroll
            for (int ni = 0; ni < 4; ++ni)
                acc[mi][ni] = __builtin_amdgcn_mfma_f32_16x16x32_bf16(
                    af[mi], bf[ni], acc[mi][ni], 0, 0, 0);
    }

    // epilogue: C/D layout col = lane&15, row = quad*4 + reg  [verified m89]
#pragma unroll
    for (int mi = 0; mi < 4; ++mi) {
#pragma unroll
        for (int ni = 0; ni < 4; ++ni) {
            int col = n0 + wcol + ni * 16 + r;
#pragma unroll
            for (int p = 0; p < 4; ++p) {
                int row = m0 + wrow + mi * 16 + quad * 4 + p;
                C[(size_t)row * MM + col] = __float2bfloat16(acc[mi][ni][p]);
            }
        }
    }
}

// ---------------- routing kernels ----------------

// softmax over the capsule axis i (10 values) for each (b, j)
__global__ void k_softmax(const float* __restrict__ bl, float* __restrict__ c) {
    int b = blockIdx.x >> 2;
    int j = ((blockIdx.x & 3) << 7) + threadIdx.x;   // 4 chunks of 128 j
    const float* p = bl + (size_t)b * NC * NJ + j;
    float v[NC], mx = -1e30f;
#pragma unroll
    for (int i = 0; i < NC; ++i) { v[i] = p[i * NJ]; mx = fmaxf(mx, v[i]); }
    float s = 0.f;
#pragma unroll
    for (int i = 0; i < NC; ++i) { v[i] = __expf(v[i] - mx); s += v[i]; }
    float inv = 1.f / s;
    float* q = c + (size_t)b * NC * NJ + j;
#pragma unroll
    for (int i = 0; i < NC; ++i) q[i * NJ] = v[i] * inv;
}

// outputs[b,i,k] = squash_k( sum_j c[b,i,j] * u[b,i,j,k] )
// block = (b*NC + i), 256 threads = 4 waves, lane = k; wave streams j with stride 4
__global__ __launch_bounds__(256)
void k_caps_out(const __hip_bfloat16* __restrict__ u, const float* __restrict__ c,
                float* __restrict__ out) {
    int bi = blockIdx.x;
    int b = bi / NC, i = bi - b * NC;
    int w = threadIdx.x >> 6, k = threadIdx.x & 63;
    const __hip_bfloat16* up = u + (size_t)b * NJ * MM + i * DC + k;
    const float* cp = c + ((size_t)b * NC + i) * NJ;
    float acc = 0.f;
    for (int j = w; j < NJ; j += 4)
        acc += cp[j] * __bfloat162float(up[(size_t)j * MM]);   // 128 B coalesced row/wave

    __shared__ float red[4][DC];
    red[w][k] = acc;
    __syncthreads();
    if (w == 0) {
        float v = red[0][k] + red[1][k] + red[2][k] + red[3][k];
        float sq = v * v;
#pragma unroll
        for (int m = 32; m >= 1; m >>= 1) sq += __shfl_xor(sq, m, 64);
        out[((size_t)b * NC + i) * DC + k] = v * rsqrtf(sq + 1e-7f);
    }
}

// b_logits[b,i,j] = sum_k outputs[b,i,k] * u[b,i,j,k]
__global__ __launch_bounds__(256)
void k_caps_b(const __hip_bfloat16* __restrict__ u, const float* __restrict__ osq,
              float* __restrict__ bl) {
    int bi = blockIdx.x;
    int b = bi / NC, i = bi - b * NC;
    int w = threadIdx.x >> 6, k = threadIdx.x & 63;
    float o = osq[((size_t)b * NC + i) * DC + k];
    const __hip_bfloat16* up = u + (size_t)b * NJ * MM + i * DC + k;
    float* blp = bl + ((size_t)b * NC + i) * NJ;
    for (int j = w; j < NJ; j += 4) {
        float p = o * __bfloat162float(up[(size_t)j * MM]);
#pragma unroll
        for (int m = 32; m >= 1; m >>= 1) p += __shfl_xor(p, m, 64);  // 64-lane butterfly
        if (k == 0) blp[j] = p;
    }
}

// ---------------- launch ----------------

extern "C" void kernel_launch(void* const* d_in, const int* in_sizes, int n_in,
                              void* d_out, int out_size, void* d_ws, size_t ws_size,
                              hipStream_t stream) {
    const float* x = (const float*)d_in[0];   // [128,512,300]
    const float* W = (const float*)d_in[1];   // [1,300,640]
    float* out = (float*)d_out;               // [128,10,64]

    char* ws = (char*)d_ws;
    size_t o = 0;
    __hip_bfloat16* xb = (__hip_bfloat16*)(ws + o); o += (size_t)BQ * NJ * KP * 2;  // 41.9 MB
    __hip_bfloat16* wt = (__hip_bfloat16*)(ws + o); o += (size_t)MM * KP * 2;       // 0.4 MB
    __hip_bfloat16* u  = (__hip_bfloat16*)(ws + o); o += (size_t)BQ * NJ * MM * 2;  // 83.9 MB
    float* bl  = (float*)(ws + o); o += (size_t)BQ * NC * NJ * 4;                   // 2.6 MB
    float* c   = (float*)(ws + o); o += (size_t)BQ * NC * NJ * 4;                   // 2.6 MB
    float* osq = (float*)(ws + o);                                                  // 0.33 MB

    k_cast_x<<<(BQ * NJ * KP) / 256, 256, 0, stream>>>(x, xb);
    k_cast_w<<<(MM * KP) / 256, 256, 0, stream>>>(W, wt);
    k_zero<<<(BQ * NC * NJ) / (4 * 256), 256, 0, stream>>>((float4*)bl);
    k_gemm<<<dim3(MM / 128, (BQ * NJ) / 128), 256, 0, stream>>>(xb, wt, u);

    for (int t = 0; t < RT; ++t) {
        k_softmax<<<BQ * 4, 128, 0, stream>>>(bl, c);
        k_caps_out<<<BQ * NC, 256, 0, stream>>>(u, c, (t == RT - 1) ? out : osq);
        if (t < RT - 1)
            k_caps_b<<<BQ * NC, 256, 0, stream>>>(u, osq, bl);
    }
}

// Round 2
// 296.435 us; speedup vs baseline: 2.2434x; 2.2434x over previous
//
#include <hip/hip_runtime.h>
#include <hip/hip_bf16.h>
#include <stdint.h>

// Problem constants
#define BQ 128    // batch
#define NJ 512    // input capsules j
#define DD 300    // input dim
#define NC 10     // num_capsule i
#define DC 64     // dim_capsule k
#define MM 640    // NC*DC
#define KP 320    // K padded to multiple of 32
#define RT 5      // routing iterations

typedef __attribute__((ext_vector_type(8))) short short8;   // 8 bf16 = 4 VGPRs
typedef __attribute__((ext_vector_type(4))) float f32x4;

// ---------------- cast kernels ----------------

__global__ void k_cast_x(const float* __restrict__ x, __hip_bfloat16* __restrict__ xb) {
    int idx = blockIdx.x * 256 + threadIdx.x;          // 65536*320 total, exact grid
    int row = idx / KP, col = idx - row * KP;
    float v = (col < DD) ? x[(size_t)row * DD + col] : 0.f;
    xb[idx] = __float2bfloat16(v);
}

__global__ void k_cast_w(const float* __restrict__ w, __hip_bfloat16* __restrict__ wt) {
    int idx = blockIdx.x * 256 + threadIdx.x;          // 640*320 total, exact grid
    int m = idx / KP, k = idx - m * KP;
    float v = (k < DD) ? w[(size_t)k * MM + m] : 0.f;  // transpose: Wt[m][k] = W[k][m]
    wt[idx] = __float2bfloat16(v);
}

// ---------------- MFMA GEMM: u[65536][640] = xb[65536][320] * Wt^T ----------------
// (unchanged from round 1 — passed correctness; will be next round's target)

__global__ __launch_bounds__(256)
void k_gemm(const __hip_bfloat16* __restrict__ A,
            const __hip_bfloat16* __restrict__ Bt,
            __hip_bfloat16* __restrict__ C) {
    __shared__ __align__(16) __hip_bfloat16 As[128 * 32];
    __shared__ __align__(16) __hip_bfloat16 Bs[128 * 32];

    const int m0 = blockIdx.y * 128;
    const int n0 = blockIdx.x * 128;
    const int t  = threadIdx.x;
    const int w  = t >> 6, lane = t & 63;
    const int wrow = (w >> 1) * 64, wcol = (w & 1) * 64;
    const int quad = lane >> 4, r = lane & 15;

    f32x4 acc[4][4] = {};

    const __hip_bfloat16* ag = A  + (size_t)(m0 + (t >> 2)) * KP + (t & 3) * 8;
    const __hip_bfloat16* bg = Bt + (size_t)(n0 + (t >> 2)) * KP + (t & 3) * 8;

    for (int kt = 0; kt < KP / 32; ++kt) {
        __syncthreads();
        __builtin_amdgcn_global_load_lds(
            (const __attribute__((address_space(1))) void*)(ag + kt * 32),
            (__attribute__((address_space(3))) void*)(&As[t * 8]), 16, 0, 0);
        __builtin_amdgcn_global_load_lds(
            (const __attribute__((address_space(1))) void*)(ag + 64 * KP + kt * 32),
            (__attribute__((address_space(3))) void*)(&As[2048 + t * 8]), 16, 0, 0);
        __builtin_amdgcn_global_load_lds(
            (const __attribute__((address_space(1))) void*)(bg + kt * 32),
            (__attribute__((address_space(3))) void*)(&Bs[t * 8]), 16, 0, 0);
        __builtin_amdgcn_global_load_lds(
            (const __attribute__((address_space(1))) void*)(bg + 64 * KP + kt * 32),
            (__attribute__((address_space(3))) void*)(&Bs[2048 + t * 8]), 16, 0, 0);
        __syncthreads();

        short8 af[4], bf[4];
#pragma unroll
        for (int mi = 0; mi < 4; ++mi)
            af[mi] = *(const short8*)&As[(wrow + mi * 16 + r) * 32 + quad * 8];
#pragma unroll
        for (int ni = 0; ni < 4; ++ni)
            bf[ni] = *(const short8*)&Bs[(wcol + ni * 16 + r) * 32 + quad * 8];
#pragma unroll
        for (int mi = 0; mi < 4; ++mi)
#pragma unroll
            for (int ni = 0; ni < 4; ++ni)
                acc[mi][ni] = __builtin_amdgcn_mfma_f32_16x16x32_bf16(
                    af[mi], bf[ni], acc[mi][ni], 0, 0, 0);
    }

#pragma unroll
    for (int mi = 0; mi < 4; ++mi) {
#pragma unroll
        for (int ni = 0; ni < 4; ++ni) {
            int col = n0 + wcol + ni * 16 + r;
#pragma unroll
            for (int p = 0; p < 4; ++p) {
                int row = m0 + wrow + mi * 16 + quad * 4 + p;
                C[(size_t)row * MM + col] = __float2bfloat16(acc[mi][ni][p]);
            }
        }
    }
}

// ---------------- fused routing pass ----------------
// One pass over u per routing iteration: bl-update (from out_prev) + softmax
// + c-weighted partial sum, all in-block. Block = (b, quarter q of j-range).
// 512 threads; 8 tiles of TJ=16 j each (contiguous 20480 B per tile),
// register->LDS software-pipelined staging (next tile's loads in flight
// during current tile's compute). thread: jd = t>>5 (16 j), kg = t&31 (2 k).

#define TJ 16
#define NT 8
#define TILE_BYTES (TJ * MM * 2)   // 20480

__global__ __launch_bounds__(512)
void k_pass(const __hip_bfloat16* __restrict__ u, const float* __restrict__ osq,
            float* __restrict__ pbuf, int it) {
    // smem carve: ub 20480 | red 32*161*4=20608 | blj 640 | outl 2560  (44288 B)
    __shared__ __align__(16) char smem[TILE_BYTES + 32 * 161 * 4 + 160 * 4 + 640 * 4];
    ushort* ub   = (ushort*)smem;                          // [16][640] bf16 tile
    float*  red  = (float*)(smem + TILE_BYTES);            // [32][161] padded
    float*  blj  = (float*)(smem + TILE_BYTES + 20608);    // [160] = [jd][i]
    float*  outl = (float*)(smem + TILE_BYTES + 20608 + 640); // [640] out_prev
    float*  pored = (float*)smem;                          // reuse at end (40960 B)

    const int t   = threadIdx.x;
    const int blk = blockIdx.x;
    const int b   = blk >> 2, q = blk & 3;
    const int jd  = t >> 5, kg = t & 31;

    if (it > 0 && t < 160)   // stage out_prev (visible after first tile barriers)
        ((float4*)outl)[t] = ((const float4*)(osq + (size_t)b * MM))[t];

    const char* ubase = (const char*)(u + (size_t)(b * NJ + q * 128) * MM);

    // preload tile 0 into registers
    uint4 sa = *(const uint4*)(ubase + t * 16);
    uint4 sb = *(const uint4*)(ubase + 8192 + t * 16);
    uint2 sc = *(const uint2*)(ubase + 16384 + t * 8);

    float po[20];
#pragma unroll
    for (int e = 0; e < 20; ++e) po[e] = 0.f;

    for (int tt = 0; tt < NT; ++tt) {
        uint4 na, nb; uint2 nc2;
        if (tt + 1 < NT) {   // issue next tile's loads BEFORE compute (stay in flight)
            const char* ns = ubase + (size_t)(tt + 1) * TILE_BYTES;
            na  = *(const uint4*)(ns + t * 16);
            nb  = *(const uint4*)(ns + 8192 + t * 16);
            nc2 = *(const uint2*)(ns + 16384 + t * 8);
        }
        __syncthreads();                       // prev tile's compute done
        *(uint4*)((char*)ub + t * 16)        = sa;
        *(uint4*)((char*)ub + 8192 + t * 16) = sb;
        *(uint2*)((char*)ub + 16384 + t * 8) = sc;
        __syncthreads();                       // tile visible

        const ushort* urow = ub + jd * MM;
        float c[10];
        if (it > 0) {
            // bl partial over this thread's 2 k values; LDS-reduce over 32 kg
#pragma unroll
            for (int i = 0; i < 10; ++i) {
                uint up = *(const uint*)(urow + i * 64 + kg * 2);
                float u0 = __uint_as_float(up << 16);
                float u1 = __uint_as_float(up & 0xffff0000u);
                float2 oo = *(const float2*)(outl + i * 64 + kg * 2);
                red[kg * 161 + jd * 10 + i] = u0 * oo.x + u1 * oo.y;
            }
            __syncthreads();
            if (t < 160) {                     // t encodes (jd*10 + i)
                float s = 0.f;
#pragma unroll
                for (int g = 0; g < 32; ++g) s += red[g * 161 + t];
                blj[t] = s;
            }
            __syncthreads();
            // softmax over i (10 values, replicated per kg — cheap)
            float bl[10], mx = -1e30f;
#pragma unroll
            for (int i = 0; i < 10; ++i) { bl[i] = blj[jd * 10 + i]; mx = fmaxf(mx, bl[i]); }
            float ssum = 0.f;
#pragma unroll
            for (int i = 0; i < 10; ++i) { bl[i] = __expf(bl[i] - mx); ssum += bl[i]; }
            float inv = 1.f / ssum;
#pragma unroll
            for (int i = 0; i < 10; ++i) c[i] = bl[i] * inv;
        } else {
#pragma unroll
            for (int i = 0; i < 10; ++i) c[i] = 0.1f;   // softmax of zeros
        }
        // c-weighted partial sum, accumulated in registers across tiles
#pragma unroll
        for (int i = 0; i < 10; ++i) {
            uint up = *(const uint*)(urow + i * 64 + kg * 2);
            float u0 = __uint_as_float(up << 16);
            float u1 = __uint_as_float(up & 0xffff0000u);
            po[i * 2 + 0] += c[i] * u0;
            po[i * 2 + 1] += c[i] * u1;
        }
        sa = na; sb = nb; sc = nc2;
    }

    // reduce po over the 16 jd groups (ub/red LDS is dead -> reuse)
    __syncthreads();
#pragma unroll
    for (int e = 0; e < 20; ++e) pored[t * 20 + e] = po[e];
    __syncthreads();
    for (int m = t; m < MM; m += 512) {
        int i = m >> 6, k = m & 63, kg2 = k >> 1, kd = k & 1;
        float s = 0.f;
#pragma unroll
        for (int j2 = 0; j2 < 16; ++j2) s += pored[(j2 * 32 + kg2) * 20 + i * 2 + kd];
        pbuf[(size_t)blk * MM + m] = s;
    }
}

// squash: sum the 4 per-quarter partials, normalize each (b,i) 64-vector
__global__ __launch_bounds__(640)
void k_squash(const float* __restrict__ pbuf, float* __restrict__ dst) {
    int b = blockIdx.x, t = threadIdx.x;     // t = i*64 + k; wave = i
    float s = 0.f;
#pragma unroll
    for (int qq = 0; qq < 4; ++qq) s += pbuf[(size_t)(b * 4 + qq) * MM + t];
    float sq = s * s;
#pragma unroll
    for (int m = 32; m >= 1; m >>= 1) sq += __shfl_xor(sq, m, 64);
    dst[(size_t)b * MM + t] = s * rsqrtf(sq + 1e-7f);
}

// ---------------- launch ----------------

extern "C" void kernel_launch(void* const* d_in, const int* in_sizes, int n_in,
                              void* d_out, int out_size, void* d_ws, size_t ws_size,
                              hipStream_t stream) {
    const float* x = (const float*)d_in[0];   // [128,512,300]
    const float* W = (const float*)d_in[1];   // [1,300,640]
    float* out = (float*)d_out;               // [128,10,64]

    char* ws = (char*)d_ws;
    size_t o = 0;
    __hip_bfloat16* xb = (__hip_bfloat16*)(ws + o); o += (size_t)BQ * NJ * KP * 2;  // 41.9 MB
    __hip_bfloat16* wt = (__hip_bfloat16*)(ws + o); o += (size_t)MM * KP * 2;       // 0.4 MB
    __hip_bfloat16* u  = (__hip_bfloat16*)(ws + o); o += (size_t)BQ * NJ * MM * 2;  // 83.9 MB
    float* pbuf = (float*)(ws + o); o += (size_t)512 * MM * 4;                      // 1.3 MB
    float* osq  = (float*)(ws + o);                                                 // 0.33 MB

    k_cast_x<<<(BQ * NJ * KP) / 256, 256, 0, stream>>>(x, xb);
    k_cast_w<<<(MM * KP) / 256, 256, 0, stream>>>(W, wt);
    k_gemm<<<dim3(MM / 128, (BQ * NJ) / 128), 256, 0, stream>>>(xb, wt, u);

    for (int t = 0; t < RT; ++t) {
        k_pass<<<512, 512, 0, stream>>>(u, osq, pbuf, t);
        k_squash<<<BQ, 640, 0, stream>>>(pbuf, (t == RT - 1) ? out : osq);
    }
}